// Round 6
// baseline (170.867 us; speedup 1.0000x reference)
//
#include <hip/hip_runtime.h>
#include <math.h>

#define NFFT   512
#define HOP    256
#define NFREQ  257
#define NMIC   4
#define TSTART 120
#define NANG   361

static constexpr double PI_D = 3.14159265358979323846;
static constexpr float  PI_F = 3.14159265358979323846f;

// ---------------------------------------------------------------------------
// Kernel 1: windowed DFT, fp32, 4-way n-chunk split (unchanged from round 5).
// grid = 64 blocks: b = chunk*16 + m*4 + t ; 512 threads (thread = frequency).
// ---------------------------------------------------------------------------
__global__ __launch_bounds__(512)
void stft_kernel(const float* __restrict__ x,
                 float* __restrict__ part_re,
                 float* __restrict__ part_im) {
    int b = blockIdx.x;
    int chunk = b >> 4;
    int m = (b >> 2) & 3;
    int t = b & 3;
    int tid = threadIdx.x;

    __shared__ float2 tw[512];
    __shared__ float  v[128];

    {   // twiddle: angle = 2*pi*k/512
        float ang = (2.0f * PI_F / 512.0f) * (float)tid;
        float s, c;
        sincosf(ang, &s, &c);
        tw[tid] = make_float2(c, s);
    }
    if (tid < 128) {
        int n = chunk * 128 + tid;
        long base = ((long)(TSTART + t - 1) * HOP) * NMIC + m;
        v[tid] = x[base + (long)n * NMIC] * sinf(PI_F * (float)n / 512.0f);
    }
    __syncthreads();

    int f = tid;
    if (f >= NFREQ) return;
    int k = (f * (chunk * 128)) & 511;
    float re = 0.0f, im = 0.0f;
#pragma unroll 4
    for (int j = 0; j < 128; ++j) {
        float vn = v[j];
        float2 cs = tw[k];
        re += vn * cs.x;
        im -= vn * cs.y;
        k = (k + f) & 511;
    }
    int id = f * 16 + m * 4 + t;
    part_re[chunk * 4112 + id] = re;
    part_im[chunk * 4112 + id] = im;
}

// ---------------------------------------------------------------------------
// Kernel 2: fused eig + music. 361 blocks (block = angle) x 512 threads
// (thread = frequency). Each block REDUNDANTLY computes the fp32 Jacobi
// eigensolve for its freqs — redundancy is throughput-cheap (~6 us across the
// whole grid) and makes the projector coefficients thread-local (registers),
// eliminating the separate eig dispatch, its launch gap, and the coef
// global round-trip. No cross-block dependency inside this kernel.
// ---------------------------------------------------------------------------
__global__ __launch_bounds__(512)
void eig_music_kernel(const float* __restrict__ part_re,
                      const float* __restrict__ part_im,
                      float* __restrict__ out) {
    int a = blockIdx.x;
    int tid = threadIdx.x;

    float r = 0.0f;
    if (tid < NFREQ) {
        int f = tid;

        // ---- combine the 4 stft chunks ----
        float Xr[4][4], Xi[4][4];                     // [m][t]
#pragma unroll
        for (int m = 0; m < 4; ++m)
#pragma unroll
            for (int t = 0; t < 4; ++t) {
                int id = f * 16 + m * 4 + t;
                Xr[m][t] = part_re[id] + part_re[4112 + id]
                         + part_re[2 * 4112 + id] + part_re[3 * 4112 + id];
                Xi[m][t] = part_im[id] + part_im[4112 + id]
                         + part_im[2 * 4112 + id] + part_im[3 * 4112 + id];
            }

        // ---- 4x4 Hermitian covariance ----
        float Ar[4][4], Ai[4][4];
#pragma unroll
        for (int m = 0; m < 4; ++m)
#pragma unroll
            for (int n = 0; n < 4; ++n) {
                float rr = 0.0f, ii = 0.0f;
#pragma unroll
                for (int t = 0; t < 4; ++t) {
                    rr += Xr[m][t] * Xr[n][t] + Xi[m][t] * Xi[n][t];
                    ii += Xi[m][t] * Xr[n][t] - Xr[m][t] * Xi[n][t];
                }
                Ar[m][n] = rr;
                Ai[m][n] = ii;
            }

        // ---- complex Jacobi, 6 sweeps, branchless ----
        float Vr[4][4] = {{1,0,0,0},{0,1,0,0},{0,0,1,0},{0,0,0,1}};
        float Vi[4][4] = {{0,0,0,0},{0,0,0,0},{0,0,0,0},{0,0,0,0}};

        for (int sweep = 0; sweep < 6; ++sweep) {
#pragma unroll
            for (int p = 0; p < 3; ++p)
#pragma unroll
                for (int q = p + 1; q < 4; ++q) {
                    float ar = Ar[p][q], ai = Ai[p][q];
                    float n2 = ar * ar + ai * ai;
                    bool ok = n2 > 1e-24f;
                    float n2s = ok ? n2 : 1.0f;
                    float inv = 1.0f / sqrtf(n2s);        // 1/|apq|
                    float er = ar * inv, ei = ai * inv;   // e^{i alpha}
                    float tau = (Ar[q][q] - Ar[p][p]) * (0.5f * inv * (ok ? 1.0f : 0.0f));
                    float t_ = (tau >= 0.0f ? 1.0f : -1.0f) /
                               (fabsf(tau) + sqrtf(1.0f + tau * tau));
                    float c = ok ? 1.0f / sqrtf(1.0f + t_ * t_) : 1.0f;
                    float s = ok ? t_ * c : 0.0f;
                    // A <- A J (columns)
#pragma unroll
                    for (int k = 0; k < 4; ++k) {
                        float apr = Ar[k][p], api = Ai[k][p];
                        float aqr = Ar[k][q], aqi = Ai[k][q];
                        float tr = er * aqr + ei * aqi;
                        float ti = er * aqi - ei * aqr;
                        Ar[k][p] = c * apr - s * tr;
                        Ai[k][p] = c * api - s * ti;
                        float ur = er * apr - ei * api;
                        float ui = er * api + ei * apr;
                        Ar[k][q] = s * ur + c * aqr;
                        Ai[k][q] = s * ui + c * aqi;
                    }
                    // A <- J^H A (rows)
#pragma unroll
                    for (int k = 0; k < 4; ++k) {
                        float apr = Ar[p][k], api = Ai[p][k];
                        float aqr = Ar[q][k], aqi = Ai[q][k];
                        float tr = er * aqr - ei * aqi;
                        float ti = er * aqi + ei * aqr;
                        Ar[p][k] = c * apr - s * tr;
                        Ai[p][k] = c * api - s * ti;
                        float ur = er * apr + ei * api;
                        float ui = er * api - ei * apr;
                        Ar[q][k] = s * ur + c * aqr;
                        Ai[q][k] = s * ui + c * aqi;
                    }
                    // V <- V J (columns)
#pragma unroll
                    for (int k = 0; k < 4; ++k) {
                        float apr = Vr[k][p], api = Vi[k][p];
                        float aqr = Vr[k][q], aqi = Vi[k][q];
                        float tr = er * aqr + ei * aqi;
                        float ti = er * aqi - ei * aqr;
                        Vr[k][p] = c * apr - s * tr;
                        Vi[k][p] = c * api - s * ti;
                        float ur = er * apr - ei * api;
                        float ui = er * api + ei * apr;
                        Vr[k][q] = s * ur + c * aqr;
                        Vi[k][q] = s * ui + c * aqi;
                    }
                }
        }

        // ---- branchless selection of the 2 smallest eigenvalues ----
        float dd[4] = {Ar[0][0], Ar[1][1], Ar[2][2], Ar[3][3]};
        float w[4];
#pragma unroll
        for (int j = 0; j < 4; ++j) {
            int rank = 0;
#pragma unroll
            for (int k = 0; k < 4; ++k) {
                if (k == j) continue;
                bool less = (dd[k] < dd[j]) || (dd[k] == dd[j] && k < j);
                rank += less ? 1 : 0;
            }
            w[j] = (rank < 2) ? 1.0f : 0.0f;
        }

        // ---- projector reduced to the 7 scalars music needs ----
        float s1r = 0.f, s1i = 0.f, s2r = 0.f, s2i = 0.f, s3r = 0.f, s3i = 0.f, trc = 0.f;
#pragma unroll
        for (int j = 0; j < 4; ++j) {
            float wj = w[j];
            s1r += wj * (Vr[0][j]*Vr[1][j] + Vi[0][j]*Vi[1][j]
                       + Vr[1][j]*Vr[2][j] + Vi[1][j]*Vi[2][j]
                       + Vr[2][j]*Vr[3][j] + Vi[2][j]*Vi[3][j]);
            s1i += wj * (Vi[0][j]*Vr[1][j] - Vr[0][j]*Vi[1][j]
                       + Vi[1][j]*Vr[2][j] - Vr[1][j]*Vi[2][j]
                       + Vi[2][j]*Vr[3][j] - Vr[2][j]*Vi[3][j]);
            s2r += wj * (Vr[0][j]*Vr[2][j] + Vi[0][j]*Vi[2][j]
                       + Vr[1][j]*Vr[3][j] + Vi[1][j]*Vi[3][j]);
            s2i += wj * (Vi[0][j]*Vr[2][j] - Vr[0][j]*Vi[2][j]
                       + Vi[1][j]*Vr[3][j] - Vr[1][j]*Vi[3][j]);
            s3r += wj * (Vr[0][j]*Vr[3][j] + Vi[0][j]*Vi[3][j]);
            s3i += wj * (Vi[0][j]*Vr[3][j] - Vr[0][j]*Vi[3][j]);
            trc += wj * (Vr[0][j]*Vr[0][j] + Vi[0][j]*Vi[0][j]
                       + Vr[1][j]*Vr[1][j] + Vi[1][j]*Vi[1][j]
                       + Vr[2][j]*Vr[2][j] + Vi[2][j]*Vi[2][j]
                       + Vr[3][j]*Vr[3][j] + Vi[3][j]*Vi[3][j]);
        }

        // ---- music for this block's angle, this thread's frequency ----
        float theta = (-90.0f + 0.5f * (float)a) * (PI_F / 180.0f);
        float freq = 31.25f * (float)f;
        float phi = (float)(2.0 * PI_D * 0.04 / 343.0) * sinf(theta) * freq;
        float s1, c1;
        sincosf(phi, &s1, &c1);
        float c2 = c1 * c1 - s1 * s1;
        float s2 = 2.0f * s1 * c1;
        float c3 = c1 * c2 - s1 * s2;
        float s3 = s1 * c2 + c1 * s2;
        float val = trc + 2.0f * (c1 * s1r - s1 * s1i
                                + c2 * s2r - s2 * s2i
                                + c3 * s3r - s3 * s3i);
        r = 1.0f / (val + 1e-8f);
    }

    // ---- reduce over the block's 8 waves ----
#pragma unroll
    for (int off = 32; off > 0; off >>= 1)
        r += __shfl_down(r, off, 64);
    __shared__ float ps[8];
    if ((tid & 63) == 0) ps[tid >> 6] = r;
    __syncthreads();
    if (tid == 0)
        out[a] = (ps[0] + ps[1] + ps[2] + ps[3]
                + ps[4] + ps[5] + ps[6] + ps[7]) / 257.0f;
}

extern "C" void kernel_launch(void* const* d_in, const int* in_sizes, int n_in,
                              void* d_out, int out_size, void* d_ws, size_t ws_size,
                              hipStream_t stream) {
    const float* x = (const float*)d_in[0];
    float* out = (float*)d_out;

    // ws layout (floats): part_re 4*4112 | part_im 4*4112   (131584 B)
    float* part_re = (float*)d_ws;
    float* part_im = part_re + 4 * 4112;

    stft_kernel<<<64, 512, 0, stream>>>(x, part_re, part_im);
    eig_music_kernel<<<NANG, 512, 0, stream>>>(part_re, part_im, out);
}

// Round 8
// 130.402 us; speedup vs baseline: 1.3103x; 1.3103x over previous
//
#include <hip/hip_runtime.h>
#include <math.h>

#define NFFT   512
#define HOP    256
#define NFREQ  257
#define NMIC   4
#define TSTART 120
#define NANG   361
#define FG     16      // frequencies per block in the fused kernel
#define NBLK   17      // ceil(257/16)

static constexpr double PI_D = 3.14159265358979323846;
static constexpr float  PI_F = 3.14159265358979323846f;

// ---------------------------------------------------------------------------
// Kernel 1: fused STFT + eigensolve, NO redundancy (round-6 lesson).
// 17 blocks x 256 threads. thread = (mt, f_local): mt=tid>>4 encodes (m,t),
// fl=tid&15 the frequency within this block's group of 16.
// Phase A: stage the 1280 needed samples (frames 119..122, 4 mics) + win +
//          twiddle tables into LDS; each thread runs the full 512-tap DFT
//          for its (f,m,t). Lanes in a 16-lane group share (m,t) and n ->
//          LDS broadcast reads.
// Phase B: handoff X[f][m][t] through a [16][16] LDS tile; threads 0..15
//          (one per frequency) run the register-resident fp32 complex Jacobi
//          (identical math to round 5) and write the 7 music coefficients.
// __launch_bounds__(256,1): 1 wave/SIMD -> VGPR budget ample, no spills.
// ---------------------------------------------------------------------------
__global__ __launch_bounds__(256, 1)
void stft_eig_kernel(const float* __restrict__ x,
                     float* __restrict__ coef) {
    int tid = threadIdx.x;            // 0..255
    int fl  = tid & 15;
    int mt  = tid >> 4;               // 0..15
    int m   = mt >> 2;
    int t   = mt & 3;
    int f   = blockIdx.x * FG + fl;

    __shared__ float  xl[1280 * 4];   // samples 30464..31743, [s][mic]
    __shared__ float  win[512];
    __shared__ float2 tw[512];
    __shared__ float  Xre[16][16];    // [mt][fl]
    __shared__ float  Xim[16][16];

    // stage x: frame TSTART+t starts at sample (TSTART+t-1)*HOP = 30464+t*256
    {
        const float4* xv = (const float4*)(x + 30464 * 4);  // 16B-aligned
        float4* xl4 = (float4*)xl;
        for (int i = tid; i < 1280; i += 256) xl4[i] = xv[i];
    }
    for (int i = tid; i < 512; i += 256) {
        win[i] = sinf(PI_F * (float)i / 512.0f);
        float s, c;
        sincosf((2.0f * PI_F / 512.0f) * (float)i, &s, &c);
        tw[i] = make_float2(c, s);
    }
    __syncthreads();

    float re = 0.0f, im = 0.0f;
    if (f < NFREQ) {
        int toff = t * 256;
        int k = 0;                    // (f*n)&511 at n=0
#pragma unroll 8
        for (int n = 0; n < 512; ++n) {
            float v = xl[(toff + n) * 4 + m] * win[n];
            float2 cs = tw[k];
            re += v * cs.x;
            im -= v * cs.y;
            k = (k + f) & 511;
        }
    }
    Xre[mt][fl] = re;
    Xim[mt][fl] = im;
    __syncthreads();

    // ---- Phase B: one thread per frequency ----
    int ff = blockIdx.x * FG + tid;
    if (tid < 16 && ff < NFREQ) {
        float Xr[4][4], Xi[4][4];     // [m][t]
#pragma unroll
        for (int mm = 0; mm < 4; ++mm)
#pragma unroll
            for (int tt = 0; tt < 4; ++tt) {
                Xr[mm][tt] = Xre[mm * 4 + tt][tid];
                Xi[mm][tt] = Xim[mm * 4 + tt][tid];
            }

        float Ar[4][4], Ai[4][4];
#pragma unroll
        for (int mm = 0; mm < 4; ++mm)
#pragma unroll
            for (int nn = 0; nn < 4; ++nn) {
                float rr = 0.0f, ii = 0.0f;
#pragma unroll
                for (int tt = 0; tt < 4; ++tt) {
                    rr += Xr[mm][tt] * Xr[nn][tt] + Xi[mm][tt] * Xi[nn][tt];
                    ii += Xi[mm][tt] * Xr[nn][tt] - Xr[mm][tt] * Xi[nn][tt];
                }
                Ar[mm][nn] = rr;
                Ai[mm][nn] = ii;
            }

        float Vr[4][4] = {{1,0,0,0},{0,1,0,0},{0,0,1,0},{0,0,0,1}};
        float Vi[4][4] = {{0,0,0,0},{0,0,0,0},{0,0,0,0},{0,0,0,0}};

        for (int sweep = 0; sweep < 6; ++sweep) {
#pragma unroll
            for (int p = 0; p < 3; ++p)
#pragma unroll
                for (int q = p + 1; q < 4; ++q) {
                    float ar = Ar[p][q], ai = Ai[p][q];
                    float n2 = ar * ar + ai * ai;
                    bool ok = n2 > 1e-24f;
                    float n2s = ok ? n2 : 1.0f;
                    float inv = 1.0f / sqrtf(n2s);
                    float er = ar * inv, ei = ai * inv;
                    float tau = (Ar[q][q] - Ar[p][p]) * (0.5f * inv * (ok ? 1.0f : 0.0f));
                    float t_ = (tau >= 0.0f ? 1.0f : -1.0f) /
                               (fabsf(tau) + sqrtf(1.0f + tau * tau));
                    float c = ok ? 1.0f / sqrtf(1.0f + t_ * t_) : 1.0f;
                    float s = ok ? t_ * c : 0.0f;
#pragma unroll
                    for (int k = 0; k < 4; ++k) {   // A <- A J
                        float apr = Ar[k][p], api = Ai[k][p];
                        float aqr = Ar[k][q], aqi = Ai[k][q];
                        float tr = er * aqr + ei * aqi;
                        float ti = er * aqi - ei * aqr;
                        Ar[k][p] = c * apr - s * tr;
                        Ai[k][p] = c * api - s * ti;
                        float ur = er * apr - ei * api;
                        float ui = er * api + ei * apr;
                        Ar[k][q] = s * ur + c * aqr;
                        Ai[k][q] = s * ui + c * aqi;
                    }
#pragma unroll
                    for (int k = 0; k < 4; ++k) {   // A <- J^H A
                        float apr = Ar[p][k], api = Ai[p][k];
                        float aqr = Ar[q][k], aqi = Ai[q][k];
                        float tr = er * aqr - ei * aqi;
                        float ti = er * aqi + ei * aqr;
                        Ar[p][k] = c * apr - s * tr;
                        Ai[p][k] = c * api - s * ti;
                        float ur = er * apr + ei * api;
                        float ui = er * api - ei * apr;
                        Ar[q][k] = s * ur + c * aqr;
                        Ai[q][k] = s * ui + c * aqi;
                    }
#pragma unroll
                    for (int k = 0; k < 4; ++k) {   // V <- V J
                        float apr = Vr[k][p], api = Vi[k][p];
                        float aqr = Vr[k][q], aqi = Vi[k][q];
                        float tr = er * aqr + ei * aqi;
                        float ti = er * aqi - ei * aqr;
                        Vr[k][p] = c * apr - s * tr;
                        Vi[k][p] = c * api - s * ti;
                        float ur = er * apr - ei * api;
                        float ui = er * api + ei * apr;
                        Vr[k][q] = s * ur + c * aqr;
                        Vi[k][q] = s * ui + c * aqi;
                    }
                }
        }

        float dd[4] = {Ar[0][0], Ar[1][1], Ar[2][2], Ar[3][3]};
        float w[4];
#pragma unroll
        for (int j = 0; j < 4; ++j) {
            int rank = 0;
#pragma unroll
            for (int k = 0; k < 4; ++k) {
                if (k == j) continue;
                bool less = (dd[k] < dd[j]) || (dd[k] == dd[j] && k < j);
                rank += less ? 1 : 0;
            }
            w[j] = (rank < 2) ? 1.0f : 0.0f;
        }

        float s1r = 0.f, s1i = 0.f, s2r = 0.f, s2i = 0.f, s3r = 0.f, s3i = 0.f, trc = 0.f;
#pragma unroll
        for (int j = 0; j < 4; ++j) {
            float wj = w[j];
            s1r += wj * (Vr[0][j]*Vr[1][j] + Vi[0][j]*Vi[1][j]
                       + Vr[1][j]*Vr[2][j] + Vi[1][j]*Vi[2][j]
                       + Vr[2][j]*Vr[3][j] + Vi[2][j]*Vi[3][j]);
            s1i += wj * (Vi[0][j]*Vr[1][j] - Vr[0][j]*Vi[1][j]
                       + Vi[1][j]*Vr[2][j] - Vr[1][j]*Vi[2][j]
                       + Vi[2][j]*Vr[3][j] - Vr[2][j]*Vi[3][j]);
            s2r += wj * (Vr[0][j]*Vr[2][j] + Vi[0][j]*Vi[2][j]
                       + Vr[1][j]*Vr[3][j] + Vi[1][j]*Vi[3][j]);
            s2i += wj * (Vi[0][j]*Vr[2][j] - Vr[0][j]*Vi[2][j]
                       + Vi[1][j]*Vr[3][j] - Vr[1][j]*Vi[3][j]);
            s3r += wj * (Vr[0][j]*Vr[3][j] + Vi[0][j]*Vi[3][j]);
            s3i += wj * (Vi[0][j]*Vr[3][j] - Vr[0][j]*Vi[3][j]);
            trc += wj * (Vr[0][j]*Vr[0][j] + Vi[0][j]*Vi[0][j]
                       + Vr[1][j]*Vr[1][j] + Vi[1][j]*Vi[1][j]
                       + Vr[2][j]*Vr[2][j] + Vi[2][j]*Vi[2][j]
                       + Vr[3][j]*Vr[3][j] + Vi[3][j]*Vi[3][j]);
        }
        float* cf = coef + ff * 8;
        cf[0] = s1r; cf[1] = s1i; cf[2] = s2r; cf[3] = s2i;
        cf[4] = s3r; cf[5] = s3i; cf[6] = trc; cf[7] = 0.0f;
    }
}

// ---------------------------------------------------------------------------
// Kernel 2: MUSIC spectrum (round-5 version). 361 blocks x 320 threads.
// ---------------------------------------------------------------------------
__global__ __launch_bounds__(320)
void music_kernel(const float* __restrict__ coef,
                  float* __restrict__ out) {
    int a = blockIdx.x;
    int tid = threadIdx.x;
    float r = 0.0f;
    if (tid < NFREQ) {
        const float4* cf4 = (const float4*)(coef + tid * 8);
        float4 cA = cf4[0];           // S1r S1i S2r S2i
        float4 cB = cf4[1];           // S3r S3i tr  pad
        float theta = (-90.0f + 0.5f * (float)a) * (PI_F / 180.0f);
        float freq = 31.25f * (float)tid;
        float phi = (float)(2.0 * PI_D * 0.04 / 343.0) * sinf(theta) * freq;
        float s1, c1;
        sincosf(phi, &s1, &c1);
        float c2 = c1 * c1 - s1 * s1;
        float s2 = 2.0f * s1 * c1;
        float c3 = c1 * c2 - s1 * s2;
        float s3 = s1 * c2 + c1 * s2;
        float val = cB.z + 2.0f * (c1 * cA.x - s1 * cA.y
                                 + c2 * cA.z - s2 * cA.w
                                 + c3 * cB.x - s3 * cB.y);
        r = 1.0f / (val + 1e-8f);
    }
#pragma unroll
    for (int off = 32; off > 0; off >>= 1)
        r += __shfl_down(r, off, 64);
    __shared__ float ps[5];
    if ((tid & 63) == 0) ps[tid >> 6] = r;
    __syncthreads();
    if (tid == 0)
        out[a] = (ps[0] + ps[1] + ps[2] + ps[3] + ps[4]) / 257.0f;
}

extern "C" void kernel_launch(void* const* d_in, const int* in_sizes, int n_in,
                              void* d_out, int out_size, void* d_ws, size_t ws_size,
                              hipStream_t stream) {
    const float* x = (const float*)d_in[0];
    float* out = (float*)d_out;
    float* coef = (float*)d_ws;   // 257*8 floats

    stft_eig_kernel<<<NBLK, 256, 0, stream>>>(x, coef);
    music_kernel<<<NANG, 320, 0, stream>>>(coef, out);
}

// Round 9
// 120.022 us; speedup vs baseline: 1.4236x; 1.0865x over previous
//
#include <hip/hip_runtime.h>
#include <math.h>

#define NFFT   512
#define HOP    256
#define NFREQ  257
#define NMIC   4
#define TSTART 120
#define NANG   361

static constexpr double PI_D = 3.14159265358979323846;
static constexpr float  PI_F = 3.14159265358979323846f;

// ---------------------------------------------------------------------------
// Kernel 1: fused STFT + eigensolve, one block PER FREQUENCY (257 blocks).
// 256 threads: thread = (mt, seg); mt=tid>>4 encodes (m,t), seg=tid&15.
// Each thread sums 32 taps n = seg + 16*j (stride-16 interleave):
//   - win[n] reads: same n across mt groups -> LDS broadcast, conflict-free.
//   - xl reads: bank = (4*seg+m)%32 -> <=4-way, negligible absolute cost.
//   - twiddle: in-register complex rotation recurrence (no LDS, no table):
//     start e^{-2pi i k0/512}, k0=(f*seg)&511; step e^{-2pi i kd/512},
//     kd=(16*f)&511. fp32 drift over 32 steps ~1e-6 relative.
// Then 4-step shfl_xor reduce over seg within each 16-lane group; thread 0
// runs the register-resident fp32 Jacobi (launch_bounds(256,1): no spill)
// while the other 257-1 blocks' Jacobis run concurrently on other CUs.
// ---------------------------------------------------------------------------
__global__ __launch_bounds__(256, 1)
void stft_eig_kernel(const float* __restrict__ x,
                     float* __restrict__ coef) {
    int f   = blockIdx.x;             // 0..256
    int tid = threadIdx.x;            // 0..255
    int seg = tid & 15;
    int mt  = tid >> 4;               // 0..15
    int m   = mt >> 2;
    int t   = mt & 3;

    __shared__ float xl[1280 * 4];    // samples 30464..31743, [s][mic]
    __shared__ float win[512];
    __shared__ float Xre[16];         // [mt]
    __shared__ float Xim[16];

    // stage x: frame TSTART+t starts at sample (TSTART+t-1)*HOP = 30464+t*256
    {
        const float4* xv = (const float4*)(x + 30464 * 4);  // 16B-aligned
        float4* xl4 = (float4*)xl;
#pragma unroll
        for (int i = 0; i < 5; ++i)
            xl4[tid + 256 * i] = xv[tid + 256 * i];
    }
    win[tid]       = sinf(PI_F * (float)tid / 512.0f);
    win[tid + 256] = sinf(PI_F * (float)(tid + 256) / 512.0f);
    __syncthreads();

    // ---- 32-tap DFT with register twiddle recurrence ----
    float c, s, cd, sd;
    {
        int k0 = (f * seg) & 511;
        int kd = (f * 16) & 511;
        sincosf(-2.0f * PI_F * (float)k0 / 512.0f, &s, &c);
        sincosf(-2.0f * PI_F * (float)kd / 512.0f, &sd, &cd);
    }
    float re = 0.0f, im = 0.0f;
    int toff = t * 256;
#pragma unroll 8
    for (int j = 0; j < 32; ++j) {
        int n = seg + 16 * j;
        float v = xl[(toff + n) * 4 + m] * win[n];
        re += v * c;
        im += v * s;                      // e^{-i theta}: s already negative-angle
        float cn = c * cd - s * sd;
        s = s * cd + c * sd;
        c = cn;
    }
    // reduce over the 16 segs (16-lane groups)
#pragma unroll
    for (int off = 8; off > 0; off >>= 1) {
        re += __shfl_xor(re, off, 16);
        im += __shfl_xor(im, off, 16);
    }
    if (seg == 0) { Xre[mt] = re; Xim[mt] = im; }
    __syncthreads();

    // ---- Phase B: thread 0 does covariance + Jacobi for this frequency ----
    if (tid == 0) {
        float Xr[4][4], Xi[4][4];     // [m][t]
#pragma unroll
        for (int mm = 0; mm < 4; ++mm)
#pragma unroll
            for (int tt = 0; tt < 4; ++tt) {
                Xr[mm][tt] = Xre[mm * 4 + tt];
                Xi[mm][tt] = Xim[mm * 4 + tt];
            }

        float Ar[4][4], Ai[4][4];
#pragma unroll
        for (int mm = 0; mm < 4; ++mm)
#pragma unroll
            for (int nn = 0; nn < 4; ++nn) {
                float rr = 0.0f, ii = 0.0f;
#pragma unroll
                for (int tt = 0; tt < 4; ++tt) {
                    rr += Xr[mm][tt] * Xr[nn][tt] + Xi[mm][tt] * Xi[nn][tt];
                    ii += Xi[mm][tt] * Xr[nn][tt] - Xr[mm][tt] * Xi[nn][tt];
                }
                Ar[mm][nn] = rr;
                Ai[mm][nn] = ii;
            }

        float Vr[4][4] = {{1,0,0,0},{0,1,0,0},{0,0,1,0},{0,0,0,1}};
        float Vi[4][4] = {{0,0,0,0},{0,0,0,0},{0,0,0,0},{0,0,0,0}};

        for (int sweep = 0; sweep < 6; ++sweep) {
#pragma unroll
            for (int p = 0; p < 3; ++p)
#pragma unroll
                for (int q = p + 1; q < 4; ++q) {
                    float ar = Ar[p][q], ai = Ai[p][q];
                    float n2 = ar * ar + ai * ai;
                    bool ok = n2 > 1e-24f;
                    float n2s = ok ? n2 : 1.0f;
                    float inv = 1.0f / sqrtf(n2s);
                    float er = ar * inv, ei = ai * inv;
                    float tau = (Ar[q][q] - Ar[p][p]) * (0.5f * inv * (ok ? 1.0f : 0.0f));
                    float t_ = (tau >= 0.0f ? 1.0f : -1.0f) /
                               (fabsf(tau) + sqrtf(1.0f + tau * tau));
                    float cc = ok ? 1.0f / sqrtf(1.0f + t_ * t_) : 1.0f;
                    float ss = ok ? t_ * cc : 0.0f;
#pragma unroll
                    for (int k = 0; k < 4; ++k) {   // A <- A J
                        float apr = Ar[k][p], api = Ai[k][p];
                        float aqr = Ar[k][q], aqi = Ai[k][q];
                        float tr = er * aqr + ei * aqi;
                        float ti = er * aqi - ei * aqr;
                        Ar[k][p] = cc * apr - ss * tr;
                        Ai[k][p] = cc * api - ss * ti;
                        float ur = er * apr - ei * api;
                        float ui = er * api + ei * apr;
                        Ar[k][q] = ss * ur + cc * aqr;
                        Ai[k][q] = ss * ui + cc * aqi;
                    }
#pragma unroll
                    for (int k = 0; k < 4; ++k) {   // A <- J^H A
                        float apr = Ar[p][k], api = Ai[p][k];
                        float aqr = Ar[q][k], aqi = Ai[q][k];
                        float tr = er * aqr - ei * aqi;
                        float ti = er * aqi + ei * aqr;
                        Ar[p][k] = cc * apr - ss * tr;
                        Ai[p][k] = cc * api - ss * ti;
                        float ur = er * apr + ei * api;
                        float ui = er * api - ei * apr;
                        Ar[q][k] = ss * ur + cc * aqr;
                        Ai[q][k] = ss * ui + cc * aqi;
                    }
#pragma unroll
                    for (int k = 0; k < 4; ++k) {   // V <- V J
                        float apr = Vr[k][p], api = Vi[k][p];
                        float aqr = Vr[k][q], aqi = Vi[k][q];
                        float tr = er * aqr + ei * aqi;
                        float ti = er * aqi - ei * aqr;
                        Vr[k][p] = cc * apr - ss * tr;
                        Vi[k][p] = cc * api - ss * ti;
                        float ur = er * apr - ei * api;
                        float ui = er * api + ei * apr;
                        Vr[k][q] = ss * ur + cc * aqr;
                        Vi[k][q] = ss * ui + cc * aqi;
                    }
                }
        }

        float dd[4] = {Ar[0][0], Ar[1][1], Ar[2][2], Ar[3][3]};
        float w[4];
#pragma unroll
        for (int j = 0; j < 4; ++j) {
            int rank = 0;
#pragma unroll
            for (int k = 0; k < 4; ++k) {
                if (k == j) continue;
                bool less = (dd[k] < dd[j]) || (dd[k] == dd[j] && k < j);
                rank += less ? 1 : 0;
            }
            w[j] = (rank < 2) ? 1.0f : 0.0f;
        }

        float s1r = 0.f, s1i = 0.f, s2r = 0.f, s2i = 0.f, s3r = 0.f, s3i = 0.f, trc = 0.f;
#pragma unroll
        for (int j = 0; j < 4; ++j) {
            float wj = w[j];
            s1r += wj * (Vr[0][j]*Vr[1][j] + Vi[0][j]*Vi[1][j]
                       + Vr[1][j]*Vr[2][j] + Vi[1][j]*Vi[2][j]
                       + Vr[2][j]*Vr[3][j] + Vi[2][j]*Vi[3][j]);
            s1i += wj * (Vi[0][j]*Vr[1][j] - Vr[0][j]*Vi[1][j]
                       + Vi[1][j]*Vr[2][j] - Vr[1][j]*Vi[2][j]
                       + Vi[2][j]*Vr[3][j] - Vr[2][j]*Vi[3][j]);
            s2r += wj * (Vr[0][j]*Vr[2][j] + Vi[0][j]*Vi[2][j]
                       + Vr[1][j]*Vr[3][j] + Vi[1][j]*Vi[3][j]);
            s2i += wj * (Vi[0][j]*Vr[2][j] - Vr[0][j]*Vi[2][j]
                       + Vi[1][j]*Vr[3][j] - Vr[1][j]*Vi[3][j]);
            s3r += wj * (Vr[0][j]*Vr[3][j] + Vi[0][j]*Vi[3][j]);
            s3i += wj * (Vi[0][j]*Vr[3][j] - Vr[0][j]*Vi[3][j]);
            trc += wj * (Vr[0][j]*Vr[0][j] + Vi[0][j]*Vi[0][j]
                       + Vr[1][j]*Vr[1][j] + Vi[1][j]*Vi[1][j]
                       + Vr[2][j]*Vr[2][j] + Vi[2][j]*Vi[2][j]
                       + Vr[3][j]*Vr[3][j] + Vi[3][j]*Vi[3][j]);
        }
        float* cf = coef + f * 8;
        cf[0] = s1r; cf[1] = s1i; cf[2] = s2r; cf[3] = s2i;
        cf[4] = s3r; cf[5] = s3i; cf[6] = trc; cf[7] = 0.0f;
    }
}

// ---------------------------------------------------------------------------
// Kernel 2: MUSIC spectrum. 361 blocks x 320 threads (thread = frequency).
// ---------------------------------------------------------------------------
__global__ __launch_bounds__(320)
void music_kernel(const float* __restrict__ coef,
                  float* __restrict__ out) {
    int a = blockIdx.x;
    int tid = threadIdx.x;
    float r = 0.0f;
    if (tid < NFREQ) {
        const float4* cf4 = (const float4*)(coef + tid * 8);
        float4 cA = cf4[0];           // S1r S1i S2r S2i
        float4 cB = cf4[1];           // S3r S3i tr  pad
        float theta = (-90.0f + 0.5f * (float)a) * (PI_F / 180.0f);
        float freq = 31.25f * (float)tid;
        float phi = (float)(2.0 * PI_D * 0.04 / 343.0) * sinf(theta) * freq;
        float s1, c1;
        sincosf(phi, &s1, &c1);
        float c2 = c1 * c1 - s1 * s1;
        float s2 = 2.0f * s1 * c1;
        float c3 = c1 * c2 - s1 * s2;
        float s3 = s1 * c2 + c1 * s2;
        float val = cB.z + 2.0f * (c1 * cA.x - s1 * cA.y
                                 + c2 * cA.z - s2 * cA.w
                                 + c3 * cB.x - s3 * cB.y);
        r = 1.0f / (val + 1e-8f);
    }
#pragma unroll
    for (int off = 32; off > 0; off >>= 1)
        r += __shfl_down(r, off, 64);
    __shared__ float ps[5];
    if ((tid & 63) == 0) ps[tid >> 6] = r;
    __syncthreads();
    if (tid == 0)
        out[a] = (ps[0] + ps[1] + ps[2] + ps[3] + ps[4]) / 257.0f;
}

extern "C" void kernel_launch(void* const* d_in, const int* in_sizes, int n_in,
                              void* d_out, int out_size, void* d_ws, size_t ws_size,
                              hipStream_t stream) {
    const float* x = (const float*)d_in[0];
    float* out = (float*)d_out;
    float* coef = (float*)d_ws;   // 257*8 floats

    stft_eig_kernel<<<NFREQ, 256, 0, stream>>>(x, coef);
    music_kernel<<<NANG, 320, 0, stream>>>(coef, out);
}

// Round 10
// 101.380 us; speedup vs baseline: 1.6854x; 1.1839x over previous
//
#include <hip/hip_runtime.h>
#include <math.h>

#define NFFT   512
#define HOP    256
#define NFREQ  257
#define NMIC   4
#define TSTART 120
#define NANG   361

static constexpr double PI_D = 3.14159265358979323846;
static constexpr float  PI_F = 3.14159265358979323846f;

// ---------------------------------------------------------------------------
// Kernel 1: windowed DFT, fp32, 4-way n-chunk split (round-5 structure).
// grid = 64 blocks: b = chunk*16 + m*4 + t ; 512 threads (thread = frequency).
// Twiddles via in-register rotation recurrence (validated r9, absmax 0.0):
// kills the stride-f bank-conflicted tw[k] table reads; only remaining LDS
// access is the broadcast v[j] (conflict-free).
// ---------------------------------------------------------------------------
__global__ __launch_bounds__(512)
void stft_kernel(const float* __restrict__ x,
                 float* __restrict__ part_re,
                 float* __restrict__ part_im) {
    int b = blockIdx.x;
    int chunk = b >> 4;
    int m = (b >> 2) & 3;
    int t = b & 3;
    int tid = threadIdx.x;

    __shared__ float v[128];

    if (tid < 128) {
        int n = chunk * 128 + tid;
        long base = ((long)(TSTART + t - 1) * HOP) * NMIC + m;
        v[tid] = x[base + (long)n * NMIC] * sinf(PI_F * (float)n / 512.0f);
    }
    __syncthreads();

    int f = tid;
    if (f >= NFREQ) return;

    // start angle for n0 = chunk*128, step angle for +1 tap
    float c, s, cd, sd;
    {
        int k0 = (f * (chunk * 128)) & 511;
        int kd = f & 511;
        sincosf(-2.0f * PI_F * (float)k0 / 512.0f, &s, &c);
        sincosf(-2.0f * PI_F * (float)kd / 512.0f, &sd, &cd);
    }
    float re = 0.0f, im = 0.0f;
#pragma unroll 4
    for (int j = 0; j < 128; ++j) {
        float vn = v[j];
        re += vn * c;
        im += vn * s;                  // negative-angle sin already
        float cn = c * cd - s * sd;
        s = s * cd + c * sd;
        c = cn;
    }
    int id = f * 16 + m * 4 + t;
    part_re[chunk * 4112 + id] = re;
    part_im[chunk * 4112 + id] = im;
}

// ---------------------------------------------------------------------------
// Kernel 2: combine partials -> 4x4 covariance -> complex Jacobi -> noise
// projector coefficients (round-5 structure: one FREQ PER LANE, dense waves).
// Chain-shortening vs r5: 4 sweeps (fp32 floor by sweep 3-4) and hardware
// v_rsq_f32 / v_rcp_f32 via builtins instead of IEEE div/sqrt sequences
// (~12 serialized instrs each without fast-math). Subspace invariance makes
// 1-ulp rotation-parameter error harmless.
// ---------------------------------------------------------------------------
__global__ __launch_bounds__(64, 1)
void eig_kernel(const float* __restrict__ part_re,
                const float* __restrict__ part_im,
                float* __restrict__ coef) {
    int f = blockIdx.x * blockDim.x + threadIdx.x;
    if (f >= NFREQ) return;

    float Xr[4][4], Xi[4][4];                     // [m][t]
#pragma unroll
    for (int m = 0; m < 4; ++m)
#pragma unroll
        for (int t = 0; t < 4; ++t) {
            int id = f * 16 + m * 4 + t;
            Xr[m][t] = part_re[id] + part_re[4112 + id]
                     + part_re[2 * 4112 + id] + part_re[3 * 4112 + id];
            Xi[m][t] = part_im[id] + part_im[4112 + id]
                     + part_im[2 * 4112 + id] + part_im[3 * 4112 + id];
        }

    float Ar[4][4], Ai[4][4];
#pragma unroll
    for (int m = 0; m < 4; ++m)
#pragma unroll
        for (int n = 0; n < 4; ++n) {
            float rr = 0.0f, ii = 0.0f;
#pragma unroll
            for (int t = 0; t < 4; ++t) {
                rr += Xr[m][t] * Xr[n][t] + Xi[m][t] * Xi[n][t];
                ii += Xi[m][t] * Xr[n][t] - Xr[m][t] * Xi[n][t];
            }
            Ar[m][n] = rr;
            Ai[m][n] = ii;
        }

    float Vr[4][4] = {{1,0,0,0},{0,1,0,0},{0,0,1,0},{0,0,0,1}};
    float Vi[4][4] = {{0,0,0,0},{0,0,0,0},{0,0,0,0},{0,0,0,0}};

    for (int sweep = 0; sweep < 4; ++sweep) {
#pragma unroll
        for (int p = 0; p < 3; ++p)
#pragma unroll
            for (int q = p + 1; q < 4; ++q) {
                float ar = Ar[p][q], ai = Ai[p][q];
                float n2 = ar * ar + ai * ai;
                bool ok = n2 > 1e-24f;
                float n2s = ok ? n2 : 1.0f;
                float inv = __builtin_amdgcn_rsqf(n2s);     // 1/|apq|
                float er = ar * inv, ei = ai * inv;         // e^{i alpha}
                float tau = (Ar[q][q] - Ar[p][p]) * (0.5f * inv * (ok ? 1.0f : 0.0f));
                float t_ = (tau >= 0.0f ? 1.0f : -1.0f) *
                           __builtin_amdgcn_rcpf(fabsf(tau) + sqrtf(1.0f + tau * tau));
                float c = ok ? __builtin_amdgcn_rsqf(1.0f + t_ * t_) : 1.0f;
                float s = ok ? t_ * c : 0.0f;
                // A <- A J (columns)
#pragma unroll
                for (int k = 0; k < 4; ++k) {
                    float apr = Ar[k][p], api = Ai[k][p];
                    float aqr = Ar[k][q], aqi = Ai[k][q];
                    float tr = er * aqr + ei * aqi;
                    float ti = er * aqi - ei * aqr;
                    Ar[k][p] = c * apr - s * tr;
                    Ai[k][p] = c * api - s * ti;
                    float ur = er * apr - ei * api;
                    float ui = er * api + ei * apr;
                    Ar[k][q] = s * ur + c * aqr;
                    Ai[k][q] = s * ui + c * aqi;
                }
                // A <- J^H A (rows)
#pragma unroll
                for (int k = 0; k < 4; ++k) {
                    float apr = Ar[p][k], api = Ai[p][k];
                    float aqr = Ar[q][k], aqi = Ai[q][k];
                    float tr = er * aqr - ei * aqi;
                    float ti = er * aqi + ei * aqr;
                    Ar[p][k] = c * apr - s * tr;
                    Ai[p][k] = c * api - s * ti;
                    float ur = er * apr + ei * api;
                    float ui = er * api - ei * apr;
                    Ar[q][k] = s * ur + c * aqr;
                    Ai[q][k] = s * ui + c * aqi;
                }
                // V <- V J (columns)
#pragma unroll
                for (int k = 0; k < 4; ++k) {
                    float apr = Vr[k][p], api = Vi[k][p];
                    float aqr = Vr[k][q], aqi = Vi[k][q];
                    float tr = er * aqr + ei * aqi;
                    float ti = er * aqi - ei * aqr;
                    Vr[k][p] = c * apr - s * tr;
                    Vi[k][p] = c * api - s * ti;
                    float ur = er * apr - ei * api;
                    float ui = er * api + ei * apr;
                    Vr[k][q] = s * ur + c * aqr;
                    Vi[k][q] = s * ui + c * aqi;
                }
            }
    }

    // branchless selection of the 2 smallest eigenvalues
    float dd[4] = {Ar[0][0], Ar[1][1], Ar[2][2], Ar[3][3]};
    float w[4];
#pragma unroll
    for (int j = 0; j < 4; ++j) {
        int rank = 0;
#pragma unroll
        for (int k = 0; k < 4; ++k) {
            if (k == j) continue;
            bool less = (dd[k] < dd[j]) || (dd[k] == dd[j] && k < j);
            rank += less ? 1 : 0;
        }
        w[j] = (rank < 2) ? 1.0f : 0.0f;
    }

    float s1r = 0.f, s1i = 0.f, s2r = 0.f, s2i = 0.f, s3r = 0.f, s3i = 0.f, trc = 0.f;
#pragma unroll
    for (int j = 0; j < 4; ++j) {
        float wj = w[j];
        s1r += wj * (Vr[0][j]*Vr[1][j] + Vi[0][j]*Vi[1][j]
                   + Vr[1][j]*Vr[2][j] + Vi[1][j]*Vi[2][j]
                   + Vr[2][j]*Vr[3][j] + Vi[2][j]*Vi[3][j]);
        s1i += wj * (Vi[0][j]*Vr[1][j] - Vr[0][j]*Vi[1][j]
                   + Vi[1][j]*Vr[2][j] - Vr[1][j]*Vi[2][j]
                   + Vi[2][j]*Vr[3][j] - Vr[2][j]*Vi[3][j]);
        s2r += wj * (Vr[0][j]*Vr[2][j] + Vi[0][j]*Vi[2][j]
                   + Vr[1][j]*Vr[3][j] + Vi[1][j]*Vi[3][j]);
        s2i += wj * (Vi[0][j]*Vr[2][j] - Vr[0][j]*Vi[2][j]
                   + Vi[1][j]*Vr[3][j] - Vr[1][j]*Vi[3][j]);
        s3r += wj * (Vr[0][j]*Vr[3][j] + Vi[0][j]*Vi[3][j]);
        s3i += wj * (Vi[0][j]*Vr[3][j] - Vr[0][j]*Vi[3][j]);
        trc += wj * (Vr[0][j]*Vr[0][j] + Vi[0][j]*Vi[0][j]
                   + Vr[1][j]*Vr[1][j] + Vi[1][j]*Vi[1][j]
                   + Vr[2][j]*Vr[2][j] + Vi[2][j]*Vi[2][j]
                   + Vr[3][j]*Vr[3][j] + Vi[3][j]*Vi[3][j]);
    }
    float* cf = coef + f * 8;
    cf[0] = s1r; cf[1] = s1i; cf[2] = s2r; cf[3] = s2i;
    cf[4] = s3r; cf[5] = s3i; cf[6] = trc; cf[7] = 0.0f;
}

// ---------------------------------------------------------------------------
// Kernel 3: MUSIC spectrum. 361 blocks x 320 threads (round-5 version).
// ---------------------------------------------------------------------------
__global__ __launch_bounds__(320)
void music_kernel(const float* __restrict__ coef,
                  float* __restrict__ out) {
    int a = blockIdx.x;
    int tid = threadIdx.x;
    float r = 0.0f;
    if (tid < NFREQ) {
        const float4* cf4 = (const float4*)(coef + tid * 8);
        float4 cA = cf4[0];           // S1r S1i S2r S2i
        float4 cB = cf4[1];           // S3r S3i tr  pad
        float theta = (-90.0f + 0.5f * (float)a) * (PI_F / 180.0f);
        float freq = 31.25f * (float)tid;
        float phi = (float)(2.0 * PI_D * 0.04 / 343.0) * sinf(theta) * freq;
        float s1, c1;
        sincosf(phi, &s1, &c1);
        float c2 = c1 * c1 - s1 * s1;
        float s2 = 2.0f * s1 * c1;
        float c3 = c1 * c2 - s1 * s2;
        float s3 = s1 * c2 + c1 * s2;
        float val = cB.z + 2.0f * (c1 * cA.x - s1 * cA.y
                                 + c2 * cA.z - s2 * cA.w
                                 + c3 * cB.x - s3 * cB.y);
        r = 1.0f / (val + 1e-8f);
    }
#pragma unroll
    for (int off = 32; off > 0; off >>= 1)
        r += __shfl_down(r, off, 64);
    __shared__ float ps[5];
    if ((tid & 63) == 0) ps[tid >> 6] = r;
    __syncthreads();
    if (tid == 0)
        out[a] = (ps[0] + ps[1] + ps[2] + ps[3] + ps[4]) / 257.0f;
}

extern "C" void kernel_launch(void* const* d_in, const int* in_sizes, int n_in,
                              void* d_out, int out_size, void* d_ws, size_t ws_size,
                              hipStream_t stream) {
    const float* x = (const float*)d_in[0];
    float* out = (float*)d_out;

    // ws layout (floats): part_re 4*4112 | part_im 4*4112 | coef 257*8
    float* part_re = (float*)d_ws;
    float* part_im = part_re + 4 * 4112;
    float* coef    = part_im + 4 * 4112;

    stft_kernel<<<64, 512, 0, stream>>>(x, part_re, part_im);
    eig_kernel<<<(NFREQ + 63) / 64, 64, 0, stream>>>(part_re, part_im, coef);
    music_kernel<<<NANG, 320, 0, stream>>>(coef, out);
}